// Round 1
// baseline (168.337 us; speedup 1.0000x reference)
//
#include <hip/hip_runtime.h>
#include <math.h>

// Problem constants (fixed by setup_inputs)
#define NTOK 16384
#define DDIM 4096
#define NEXP 64
#define KTOP 4
#define NGRP 8
#define LGRP 4

// GEMM tiling
#define SPLITK 4
#define BM 128
#define BK 64
#define KPER (DDIM / SPLITK)   // 1024
#define NCHUNK (KPER / BK)     // 16
#define LDP 68                 // padded LDS row stride (floats), 16B-aligned

// ws layout (floats):
//   [0, SPLITK*NTOK*NEXP)                : logit partials (16 MB)
//   [SPLITK*NTOK*NEXP, +DDIM*NEXP)       : Wt transposed [D][E] (1 MB)
// total 17.8 MB

// ---------------- Kernel 1: transpose W (E x D -> D x E), zero counts --------
__global__ __launch_bounds__(256) void prep_kernel(
    const float* __restrict__ W, float* __restrict__ Wt, float* __restrict__ counts)
{
    int idx = blockIdx.x * 256 + threadIdx.x;  // 0 .. E*D
    int e = idx >> 12;                         // / DDIM
    int d = idx & 4095;                        // % DDIM
    Wt[d * NEXP + e] = W[idx];                 // coalesced read, scattered write (1MB, cheap)
    if (blockIdx.x == 0 && threadIdx.x < NEXP) counts[threadIdx.x] = 0.0f;
}

// ---------------- Kernel 2: fp32 GEMM logits = X @ Wt, split-K ---------------
__global__ __launch_bounds__(256, 3) void gemm_kernel(
    const float* __restrict__ X, const float* __restrict__ Wt, float* __restrict__ part)
{
    __shared__ float sX[BM][LDP];   // x tile  [token][k]   34.8 KB
    __shared__ float sW[BK][LDP];   // w tile  [k][expert]  17.4 KB

    const int tid  = threadIdx.x;
    const int tb   = blockIdx.x >> 2;   // token block 0..127
    const int ks   = blockIdx.x & 3;    // k-split    0..3
    const int tok0 = tb * BM;
    const int dbase = ks * KPER;
    const int tx = tid & 15;            // expert quad: experts tx*4..tx*4+3
    const int ty = tid >> 4;            // token lane: tokens ty + 16*i (i=0..7)

    float acc[8][4] = {};

    for (int c = 0; c < NCHUNK; ++c) {
        const int d0 = dbase + c * BK;
        // ---- stage X tile (128x64 floats, 8 float4/thread, coalesced) ----
        const float* xsrc = X + (size_t)tok0 * DDIM + d0;
        #pragma unroll
        for (int k = 0; k < 8; ++k) {
            int v = tid + k * 256;
            int row = v >> 4, col = (v & 15) << 2;
            *(float4*)&sX[row][col] = *(const float4*)(xsrc + (size_t)row * DDIM + col);
        }
        // ---- stage W tile (64x64 floats, 4 float4/thread, coalesced) ----
        const float* wsrc = Wt + (size_t)d0 * NEXP;
        #pragma unroll
        for (int k = 0; k < 4; ++k) {
            int v = tid + k * 256;
            int row = v >> 4, col = (v & 15) << 2;
            *(float4*)&sW[row][col] = *(const float4*)(wsrc + row * NEXP + col);
        }
        __syncthreads();

        #pragma unroll 4
        for (int kk = 0; kk < BK; kk += 4) {
            float4 xv[8];
            #pragma unroll
            for (int i = 0; i < 8; ++i)
                xv[i] = *(const float4*)&sX[ty + 16 * i][kk];
            float4 wv[4];
            #pragma unroll
            for (int k = 0; k < 4; ++k)
                wv[k] = *(const float4*)&sW[kk + k][tx * 4];
            #pragma unroll
            for (int i = 0; i < 8; ++i) {
                #pragma unroll
                for (int k = 0; k < 4; ++k) {
                    float xvv = (k == 0) ? xv[i].x : (k == 1) ? xv[i].y
                              : (k == 2) ? xv[i].z : xv[i].w;
                    acc[i][0] = fmaf(xvv, wv[k].x, acc[i][0]);
                    acc[i][1] = fmaf(xvv, wv[k].y, acc[i][1]);
                    acc[i][2] = fmaf(xvv, wv[k].z, acc[i][2]);
                    acc[i][3] = fmaf(xvv, wv[k].w, acc[i][3]);
                }
            }
        }
        __syncthreads();
    }

    // ---- store partial logits [ks][token][expert], coalesced float4 ----
    float* dst = part + ((size_t)ks * NTOK + tok0) * NEXP;
    #pragma unroll
    for (int i = 0; i < 8; ++i) {
        float4 o = make_float4(acc[i][0], acc[i][1], acc[i][2], acc[i][3]);
        *(float4*)&dst[(size_t)(ty + 16 * i) * NEXP + tx * 4] = o;
    }
}

// ---------------- Kernel 3: softmax + group-limited top-k routing ------------
__global__ __launch_bounds__(256) void route_kernel(
    const float* __restrict__ part, float* __restrict__ outW,
    float* __restrict__ outI, float* __restrict__ counts)
{
    __shared__ int hist[NEXP];
    const int tid = threadIdx.x;
    if (tid < NEXP) hist[tid] = 0;
    __syncthreads();

    const int lane = tid & 63;
    const int wv   = tid >> 6;   // wave 0..3
    const int tok_base = blockIdx.x * 32 + wv * 8;

    for (int t = 0; t < 8; ++t) {
        const int n = tok_base + t;
        // sum split-K partials: logit for expert `lane`
        float L = 0.0f;
        #pragma unroll
        for (int s = 0; s < SPLITK; ++s)
            L += part[((size_t)s * NTOK + n) * NEXP + lane];

        // softmax over 64 experts (wave = expert axis)
        float m = L;
        #pragma unroll
        for (int off = 32; off > 0; off >>= 1) m = fmaxf(m, __shfl_xor(m, off));
        float p = expf(L - m);
        float ssum = p;
        #pragma unroll
        for (int off = 32; off > 0; off >>= 1) ssum += __shfl_xor(ssum, off);
        float score = p / ssum;

        // group max within each 8-lane group
        float gm = score;
        gm = fmaxf(gm, __shfl_xor(gm, 1));
        gm = fmaxf(gm, __shfl_xor(gm, 2));
        gm = fmaxf(gm, __shfl_xor(gm, 4));

        // gather all 8 group maxima, serial top-4 groups (ties -> lower index)
        float ga[8];
        #pragma unroll
        for (int g = 0; g < 8; ++g) ga[g] = __shfl(gm, g * 8);
        unsigned selmask = 0u;
        #pragma unroll
        for (int r = 0; r < 4; ++r) {
            float best = -INFINITY; int bg = 0;
            #pragma unroll
            for (int g = 0; g < 8; ++g) {
                bool taken  = (selmask >> g) & 1u;
                bool better = (!taken) && (ga[g] > best);
                bg   = better ? g : bg;
                best = better ? ga[g] : best;
            }
            selmask |= (1u << bg);
        }

        // mask scores of non-selected groups, then wave-wide top-4 (ties -> lower idx)
        float ms = ((selmask >> (lane >> 3)) & 1u) ? score : -INFINITY;
        float wk[4]; int wi[4];
        #pragma unroll
        for (int r = 0; r < 4; ++r) {
            float v = ms; int ix = lane;
            #pragma unroll
            for (int off = 32; off > 0; off >>= 1) {
                float vo = __shfl_xor(v, off);
                int   io = __shfl_xor(ix, off);
                if (vo > v || (vo == v && io < ix)) { v = vo; ix = io; }
            }
            wk[r] = v; wi[r] = ix;
            if (lane == ix) ms = -INFINITY;
        }

        if (lane == 0) {
            *(float4*)&outW[(size_t)n * 4] = make_float4(wk[0], wk[1], wk[2], wk[3]);
            *(float4*)&outI[(size_t)n * 4] =
                make_float4((float)wi[0], (float)wi[1], (float)wi[2], (float)wi[3]);
            atomicAdd(&hist[wi[0]], 1);
            atomicAdd(&hist[wi[1]], 1);
            atomicAdd(&hist[wi[2]], 1);
            atomicAdd(&hist[wi[3]], 1);
        }
    }

    __syncthreads();
    if (tid < NEXP) atomicAdd(&counts[tid], (float)hist[tid]);
}

extern "C" void kernel_launch(void* const* d_in, const int* in_sizes, int n_in,
                              void* d_out, int out_size, void* d_ws, size_t ws_size,
                              hipStream_t stream) {
    const float* X = (const float*)d_in[0];
    const float* W = (const float*)d_in[1];

    float* outW   = (float*)d_out;                    // [N,4] weights
    float* outI   = outW + (size_t)NTOK * KTOP;       // [N,4] indices (as float)
    float* counts = outW + (size_t)2 * NTOK * KTOP;   // [64]  counts  (as float)

    float* part = (float*)d_ws;                               // 16 MB partials
    float* Wt   = part + (size_t)SPLITK * NTOK * NEXP;        // 1 MB transposed W

    prep_kernel<<<(NEXP * DDIM) / 256, 256, 0, stream>>>(W, Wt, counts);
    gemm_kernel<<<(NTOK / BM) * SPLITK, 256, 0, stream>>>(X, Wt, part);
    route_kernel<<<NTOK / 32, 256, 0, stream>>>(part, outW, outI, counts);
}